// Round 1
// baseline (765.568 us; speedup 1.0000x reference)
//
#include <hip/hip_runtime.h>

#define NB 512
#define NT 1024
#define NK 48
#define NEGV -10000.0f
#define S_START 46
#define S_END 47

extern "C" __global__ __launch_bounds__(128)
void crf_fused(const float* __restrict__ feats, const float* __restrict__ trans,
               float* __restrict__ out)
{
    // wave 0: CRF forward (logZ).  wave 1: Viterbi + backtrace.
    // All LDS traffic is intra-wave (DS pipe is in-order per wave): no barriers.
    __shared__ unsigned char bp[NT * NK];        // 48 KB backpointers (wave 1)
    __shared__ unsigned char comp[64 * NK];      // composed chunk tag-maps
    __shared__ unsigned char boundary[64];       // chunk-entry tags
    __shared__ float eabuf[64];                  // forward broadcast buffer
    __shared__ float vbuf[64];                   // viterbi broadcast buffer

    const int b = blockIdx.x;
    const int wave = threadIdx.x >> 6;
    const int lane = threadIdx.x & 63;
    const bool act = lane < NK;
    const int n = act ? lane : 0;               // safe row index for loads
    const float* f = feats + (size_t)b * NT * NK;

    // transm[END][lane]: column-END mask applies (END row != START row)
    float tEnd = NEGV;
    if (act && lane != S_END) tEnd = trans[S_END * NK + lane];

    if (wave == 0) {
        // ---------------- forward: alpha' = M + log(E . exp(alpha-M)) + feat
        float Erow[NK];
        {
            const bool rowdead = (!act || lane == S_START);
            const float4* r4 = (const float4*)(trans + n * NK);
            #pragma unroll
            for (int q = 0; q < NK / 4; ++q) {
                float4 r = r4[q];
                const int c = 4 * q;
                float m0 = (rowdead || c + 0 == S_END) ? NEGV : r.x;
                float m1 = (rowdead || c + 1 == S_END) ? NEGV : r.y;
                float m2 = (rowdead || c + 2 == S_END) ? NEGV : r.z;
                float m3 = (rowdead || c + 3 == S_END) ? NEGV : r.w;
                Erow[c + 0] = __expf(m0);  // exp(-10000) underflows to 0: exact
                Erow[c + 1] = __expf(m1);
                Erow[c + 2] = __expf(m2);
                Erow[c + 3] = __expf(m3);
            }
        }
        // u = alpha - M (M wave-uniform, one step stale = exact max of prev alpha)
        float u = (act && lane == S_START) ? 0.0f : NEGV;
        float Muni = 0.0f;
        eabuf[lane] = __expf(u);                 // exp(0)=1 at START, else 0
        __builtin_amdgcn_wave_barrier();

        float fA = act ? f[0 * NK + lane] : 0.0f;
        float fB = act ? f[1 * NK + lane] : 0.0f;

        for (int t = 0; t < NT; ++t) {
            float fc = fA; fA = fB;
            if (t + 2 < NT) fB = act ? f[(t + 2) * NK + lane] : 0.0f;

            float ea[NK];
            {
                const float4* e4 = (const float4*)eabuf;
                #pragma unroll
                for (int q = 0; q < NK / 4; ++q) {
                    float4 r = e4[q];
                    ea[4 * q + 0] = r.x; ea[4 * q + 1] = r.y;
                    ea[4 * q + 2] = r.z; ea[4 * q + 3] = r.w;
                }
            }
            // max-tree over ea (register-only): m_e = exp(max alpha_t - M_t)
            float tm[24];
            #pragma unroll
            for (int p = 0; p < 24; ++p) tm[p] = fmaxf(ea[p], ea[p + 24]);
            #pragma unroll
            for (int p = 0; p < 12; ++p) tm[p] = fmaxf(tm[p], tm[p + 12]);
            #pragma unroll
            for (int p = 0; p < 6; ++p)  tm[p] = fmaxf(tm[p], tm[p + 6]);
            #pragma unroll
            for (int p = 0; p < 3; ++p)  tm[p] = fmaxf(tm[p], tm[p + 3]);
            float m_e = fmaxf(fmaxf(tm[0], tm[1]), tm[2]);

            float a0 = 0.f, a1 = 0.f, a2 = 0.f, a3 = 0.f;
            #pragma unroll
            for (int p = 0; p < NK; p += 4) {
                a0 = fmaf(Erow[p + 0], ea[p + 0], a0);
                a1 = fmaf(Erow[p + 1], ea[p + 1], a1);
                a2 = fmaf(Erow[p + 2], ea[p + 2], a2);
                a3 = fmaf(Erow[p + 3], ea[p + 3], a3);
            }
            float acc = (a0 + a1) + (a2 + a3);

            float dM = __logf(m_e);              // M_{t+1} = M_t + dM
            Muni += dM;
            u = __logf(acc) + fc - dM;           // log(0)=-inf propagates cleanly
            __builtin_amdgcn_wave_barrier();
            eabuf[lane] = __expf(u);
            __builtin_amdgcn_wave_barrier();
        }
        // logz = Muni + logsumexp(u + tEnd)
        float x = act ? (u + tEnd) : -INFINITY;  // -inf + finite = -inf: safe
        float M2 = x;
        #pragma unroll
        for (int off = 32; off >= 1; off >>= 1)
            M2 = fmaxf(M2, __shfl_xor(M2, off, 64));
        float e = __expf(x - M2);
        #pragma unroll
        for (int off = 32; off >= 1; off >>= 1)
            e += __shfl_xor(e, off, 64);
        if (lane == 0) out[b] = Muni + M2 + __logf(e);
    } else {
        // ---------------- viterbi: exact fp32, reference op order
        float trow[NK];
        {
            const bool rowdead = (lane == S_START);
            const float4* r4 = (const float4*)(trans + n * NK);
            #pragma unroll
            for (int q = 0; q < NK / 4; ++q) {
                float4 r = r4[q];
                const int c = 4 * q;
                trow[c + 0] = (rowdead || c + 0 == S_END) ? NEGV : r.x;
                trow[c + 1] = (rowdead || c + 1 == S_END) ? NEGV : r.y;
                trow[c + 2] = (rowdead || c + 2 == S_END) ? NEGV : r.z;
                trow[c + 3] = (rowdead || c + 3 == S_END) ? NEGV : r.w;
            }
        }
        float v = (lane == S_START) ? 0.0f : NEGV;
        vbuf[lane] = v;
        __builtin_amdgcn_wave_barrier();

        float fA = act ? f[0 * NK + lane] : 0.0f;
        float fB = act ? f[1 * NK + lane] : 0.0f;

        for (int t = 0; t < NT; ++t) {
            float fc = fA; fA = fB;
            if (t + 2 < NT) fB = act ? f[(t + 2) * NK + lane] : 0.0f;

            float va[NK];
            {
                const float4* v4 = (const float4*)vbuf;
                #pragma unroll
                for (int q = 0; q < NK / 4; ++q) {
                    float4 r = v4[q];
                    va[4 * q + 0] = r.x; va[4 * q + 1] = r.y;
                    va[4 * q + 2] = r.z; va[4 * q + 3] = r.w;
                }
            }
            // 4 strided groups; strict > keeps first occurrence within group
            float bv0 = -INFINITY, bv1 = -INFINITY, bv2 = -INFINITY, bv3 = -INFINITY;
            int   bi0 = 0, bi1 = 1, bi2 = 2, bi3 = 3;
            #pragma unroll
            for (int p = 0; p < NK; p += 4) {
                float s0 = va[p + 0] + trow[p + 0];
                float s1 = va[p + 1] + trow[p + 1];
                float s2 = va[p + 2] + trow[p + 2];
                float s3 = va[p + 3] + trow[p + 3];
                if (s0 > bv0) { bv0 = s0; bi0 = p + 0; }
                if (s1 > bv1) { bv1 = s1; bi1 = p + 1; }
                if (s2 > bv2) { bv2 = s2; bi2 = p + 2; }
                if (s3 > bv3) { bv3 = s3; bi3 = p + 3; }
            }
            // merge with first-occurrence (numpy argmax) tie-break
            float best = bv0; int bi = bi0;
            if (bv1 > best || (bv1 == best && bi1 < bi)) { best = bv1; bi = bi1; }
            if (bv2 > best || (bv2 == best && bi2 < bi)) { best = bv2; bi = bi2; }
            if (bv3 > best || (bv3 == best && bi3 < bi)) { best = bv3; bi = bi3; }

            if (act) bp[t * NK + lane] = (unsigned char)bi;  // before +feat (ref order)
            v = best + fc;
            __builtin_amdgcn_wave_barrier();
            vbuf[lane] = v;
            __builtin_amdgcn_wave_barrier();
        }
        // termination: term = v + trans[END]; first-occurrence argmax
        float xv = act ? (v + tEnd) : -INFINITY;
        int idx = act ? lane : 63;
        float val = xv;
        #pragma unroll
        for (int off = 32; off >= 1; off >>= 1) {
            float ov = __shfl_xor(val, off, 64);
            int   oi = __shfl_xor(idx, off, 64);
            if (ov > val || (ov == val && oi < idx)) { val = ov; idx = oi; }
        }
        if (lane == 0) out[NB + b] = val;
        const int last = idx;

        // ---- chunk-composed backtrace (all intra-wave LDS, in-order DS pipe)
        __builtin_amdgcn_wave_barrier();
        int cur[NK];
        #pragma unroll
        for (int k = 0; k < NK; ++k) cur[k] = k;
        const int tbase = lane * 16;                 // 64 chunks of 16 steps
        for (int i = 15; i >= 0; --i) {
            const int t = tbase + i;
            #pragma unroll
            for (int k = 0; k < NK; ++k) cur[k] = bp[t * NK + cur[k]];
        }
        #pragma unroll
        for (int k = 0; k < NK; ++k) comp[lane * NK + k] = (unsigned char)cur[k];
        __builtin_amdgcn_wave_barrier();

        if (lane == 0) {                             // serial chase over 64 maps
            int tag = last;
            for (int l = 63; l >= 0; --l) {
                boundary[l] = (unsigned char)tag;
                tag = comp[l * NK + tag];
            }
        }
        __builtin_amdgcn_wave_barrier();

        int tag = boundary[lane];
        float* pout = out + 2 * NB + (size_t)b * NT;
        for (int i = 15; i >= 0; --i) {              // re-expand: path[t]=tag, then step
            const int t = tbase + i;
            pout[t] = (float)tag;
            tag = bp[t * NK + tag];
        }
    }
}

extern "C" void kernel_launch(void* const* d_in, const int* in_sizes, int n_in,
                              void* d_out, int out_size, void* d_ws, size_t ws_size,
                              hipStream_t stream) {
    (void)in_sizes; (void)n_in; (void)d_ws; (void)ws_size; (void)out_size;
    const float* feats = (const float*)d_in[0];
    const float* trans = (const float*)d_in[1];
    float* out = (float*)d_out;
    crf_fused<<<dim3(NB), dim3(128), 0, stream>>>(feats, trans, out);
}

// Round 2
// 521.433 us; speedup vs baseline: 1.4682x; 1.4682x over previous
//
#include <hip/hip_runtime.h>

#define NB 512
#define NT 1024
#define NK 48
#define NEGV -10000.0f
#define S_START 46
#define S_END 47

__device__ __forceinline__ float rfl_f32(float x) {
    return __int_as_float(__builtin_amdgcn_readfirstlane(__float_as_int(x)));
}

extern "C" __global__ __launch_bounds__(128, 1)
void crf_fused(const float* __restrict__ feats, const float* __restrict__ trans,
               float* __restrict__ out)
{
    // wave 0: CRF forward (logZ).  wave 1: Viterbi + backtrace.
    // All LDS traffic intra-wave (DS pipe in-order per wave): no s_barrier.
    __shared__ unsigned char bp[NT * NK];        // 48 KB backpointers (wave 1)
    __shared__ unsigned char comp[64 * NK];      // composed chunk tag-maps
    __shared__ unsigned char boundary[64];       // chunk-entry tags
    __shared__ float eabuf[64];                  // forward broadcast buffer
    __shared__ float vbuf[64];                   // viterbi broadcast buffer

    const int b = blockIdx.x;
    const int wave = threadIdx.x >> 6;
    const int lane = threadIdx.x & 63;
    const bool act = lane < NK;
    const int LL = act ? lane : (NK - 1);        // clamped state: lanes 48..63 mirror 47
    const float* f = feats + (size_t)b * NT * NK;
    const float* fb = f + LL;                    // per-lane column base (always in-bounds)

    float tEnd = NEGV;
    if (act && lane != S_END) tEnd = trans[S_END * NK + lane];

    if (wave == 0) {
        // ---------------- forward: alpha' = Muni + u;  u anchored at lane 0 (u[0]==0)
        float Erow[NK];
        {
            const bool rowdead = (lane == S_START);
            const float4* r4 = (const float4*)(trans + LL * NK);
            #pragma unroll
            for (int q = 0; q < NK / 4; ++q) {
                float4 r = r4[q];
                const int c = 4 * q;
                Erow[c + 0] = (rowdead || c + 0 == S_END) ? 0.0f : __expf(r.x);
                Erow[c + 1] = (rowdead || c + 1 == S_END) ? 0.0f : __expf(r.y);
                Erow[c + 2] = (rowdead || c + 2 == S_END) ? 0.0f : __expf(r.z);
                Erow[c + 3] = (rowdead || c + 3 == S_END) ? 0.0f : __expf(r.w);
            }
        }
        float u = (lane == S_START) ? 0.0f : NEGV;
        float Muni = 0.0f;
        eabuf[lane] = __expf(u);                 // exp(0)=1 at START, else 0
        __builtin_amdgcn_wave_barrier();

        // distance-4 rotating prefetch; loads unconditional, addresses clamped
        float fr0 = fb[0 * NK], fr1 = fb[1 * NK], fr2 = fb[2 * NK], fr3 = fb[3 * NK];

        auto fstep = [&](float fc) {
            float ea[NK];
            {
                const float4* e4 = (const float4*)eabuf;
                #pragma unroll
                for (int q = 0; q < NK / 4; ++q) {
                    float4 r = e4[q];
                    ea[4 * q + 0] = r.x; ea[4 * q + 1] = r.y;
                    ea[4 * q + 2] = r.z; ea[4 * q + 3] = r.w;
                }
            }
            float a0 = 0.f, a1 = 0.f, a2 = 0.f, a3 = 0.f;
            #pragma unroll
            for (int p = 0; p < NK; p += 4) {
                a0 = fmaf(Erow[p + 0], ea[p + 0], a0);
                a1 = fmaf(Erow[p + 1], ea[p + 1], a1);
                a2 = fmaf(Erow[p + 2], ea[p + 2], a2);
                a3 = fmaf(Erow[p + 3], ea[p + 3], a3);
            }
            float acc = (a0 + a1) + (a2 + a3);   // > 0 always (ea[0]==1, Erow[n][0]>0)
            float w = __logf(acc) + fc;          // lane START: log(0)=-inf, stays -inf
            float dM = rfl_f32(w);               // lane-0 anchor (finite always)
            Muni += dM;
            u = w - dM;                          // u[0] == 0 exactly
            __builtin_amdgcn_wave_barrier();
            eabuf[lane] = __expf(u);
            __builtin_amdgcn_wave_barrier();
        };

        for (int t = 0; t < NT; t += 4) {
            { float fc = fr0; int nr = (t + 4 < NT) ? t + 4 : NT - 1; fr0 = fb[nr * NK]; fstep(fc); }
            { float fc = fr1; int nr = (t + 5 < NT) ? t + 5 : NT - 1; fr1 = fb[nr * NK]; fstep(fc); }
            { float fc = fr2; int nr = (t + 6 < NT) ? t + 6 : NT - 1; fr2 = fb[nr * NK]; fstep(fc); }
            { float fc = fr3; int nr = (t + 7 < NT) ? t + 7 : NT - 1; fr3 = fb[nr * NK]; fstep(fc); }
        }
        // logz = Muni + logsumexp(u + tEnd)
        float x = act ? (u + tEnd) : -INFINITY;
        float M2 = x;
        #pragma unroll
        for (int off = 32; off >= 1; off >>= 1)
            M2 = fmaxf(M2, __shfl_xor(M2, off, 64));
        float e = __expf(x - M2);
        #pragma unroll
        for (int off = 32; off >= 1; off >>= 1)
            e += __shfl_xor(e, off, 64);
        if (lane == 0) out[b] = Muni + M2 + __logf(e);
    } else {
        // ---------------- viterbi: exact fp32, reference op order
        float trow[NK];
        {
            const bool rowdead = (lane == S_START);
            const float4* r4 = (const float4*)(trans + LL * NK);
            #pragma unroll
            for (int q = 0; q < NK / 4; ++q) {
                float4 r = r4[q];
                const int c = 4 * q;
                trow[c + 0] = (rowdead || c + 0 == S_END) ? NEGV : r.x;
                trow[c + 1] = (rowdead || c + 1 == S_END) ? NEGV : r.y;
                trow[c + 2] = (rowdead || c + 2 == S_END) ? NEGV : r.z;
                trow[c + 3] = (rowdead || c + 3 == S_END) ? NEGV : r.w;
            }
        }
        float v = (lane == S_START) ? 0.0f : NEGV;
        vbuf[lane] = v;
        __builtin_amdgcn_wave_barrier();

        float fr0 = fb[0 * NK], fr1 = fb[1 * NK], fr2 = fb[2 * NK], fr3 = fb[3 * NK];
        const int big = 63;                      // sentinel for index min-tree

        auto vstep = [&](float fc, int tt) {
            float s[NK];
            {
                const float4* v4 = (const float4*)vbuf;
                #pragma unroll
                for (int q = 0; q < NK / 4; ++q) {
                    float4 r = v4[q];
                    s[4 * q + 0] = r.x + trow[4 * q + 0];
                    s[4 * q + 1] = r.y + trow[4 * q + 1];
                    s[4 * q + 2] = r.z + trow[4 * q + 2];
                    s[4 * q + 3] = r.w + trow[4 * q + 3];
                }
            }
            // exact max via tree (max is exactly associative; identical to np.max)
            float m16[16];
            #pragma unroll
            for (int i = 0; i < 16; ++i)
                m16[i] = fmaxf(fmaxf(s[3 * i], s[3 * i + 1]), s[3 * i + 2]);
            float m6[6];
            #pragma unroll
            for (int i = 0; i < 5; ++i)
                m6[i] = fmaxf(fmaxf(m16[3 * i], m16[3 * i + 1]), m16[3 * i + 2]);
            m6[5] = m16[15];
            float best = fmaxf(fmaxf(fmaxf(m6[0], m6[1]), m6[2]),
                               fmaxf(fmaxf(m6[3], m6[4]), m6[5]));
            // first occurrence of the max == np.argmax
            int ix[NK];
            #pragma unroll
            for (int p = 0; p < NK; ++p)
                ix[p] = (s[p] != best) ? big : p;
            int n16[16];
            #pragma unroll
            for (int i = 0; i < 16; ++i)
                n16[i] = min(min(ix[3 * i], ix[3 * i + 1]), ix[3 * i + 2]);
            int n6[6];
            #pragma unroll
            for (int i = 0; i < 5; ++i)
                n6[i] = min(min(n16[3 * i], n16[3 * i + 1]), n16[3 * i + 2]);
            n6[5] = n16[15];
            int bi = min(min(min(n6[0], n6[1]), n6[2]),
                         min(min(n6[3], n6[4]), n6[5]));

            bp[tt * NK + LL] = (unsigned char)bi; // lanes 47..63: same addr, same value
            v = best + fc;                       // reference order: +feat after argmax
            __builtin_amdgcn_wave_barrier();
            vbuf[lane] = v;
            __builtin_amdgcn_wave_barrier();
        };

        for (int t = 0; t < NT; t += 4) {
            { float fc = fr0; int nr = (t + 4 < NT) ? t + 4 : NT - 1; fr0 = fb[nr * NK]; vstep(fc, t + 0); }
            { float fc = fr1; int nr = (t + 5 < NT) ? t + 5 : NT - 1; fr1 = fb[nr * NK]; vstep(fc, t + 1); }
            { float fc = fr2; int nr = (t + 6 < NT) ? t + 6 : NT - 1; fr2 = fb[nr * NK]; vstep(fc, t + 2); }
            { float fc = fr3; int nr = (t + 7 < NT) ? t + 7 : NT - 1; fr3 = fb[nr * NK]; vstep(fc, t + 3); }
        }
        // termination: term = v + trans[END]; first-occurrence argmax
        float xv = act ? (v + tEnd) : -INFINITY;
        int idx = act ? lane : 63;
        float val = xv;
        #pragma unroll
        for (int off = 32; off >= 1; off >>= 1) {
            float ov = __shfl_xor(val, off, 64);
            int   oi = __shfl_xor(idx, off, 64);
            if (ov > val || (ov == val && oi < idx)) { val = ov; idx = oi; }
        }
        if (lane == 0) out[NB + b] = val;
        const int last = idx;

        // ---- chunk-composed backtrace (all intra-wave LDS, in-order DS pipe)
        __builtin_amdgcn_wave_barrier();
        int cur[NK];
        #pragma unroll
        for (int k = 0; k < NK; ++k) cur[k] = k;
        const int tbase = lane * 16;                 // 64 chunks of 16 steps
        for (int i = 15; i >= 0; --i) {
            const int t = tbase + i;
            #pragma unroll
            for (int k = 0; k < NK; ++k) cur[k] = bp[t * NK + cur[k]];
        }
        #pragma unroll
        for (int k = 0; k < NK; ++k) comp[lane * NK + k] = (unsigned char)cur[k];
        __builtin_amdgcn_wave_barrier();

        if (lane == 0) {                             // serial chase over 64 maps
            int tag = last;
            for (int l = 63; l >= 0; --l) {
                boundary[l] = (unsigned char)tag;
                tag = comp[l * NK + tag];
            }
        }
        __builtin_amdgcn_wave_barrier();

        int tag = boundary[lane];
        float* pout = out + 2 * NB + (size_t)b * NT;
        for (int i = 15; i >= 0; --i) {              // re-expand: path[t]=tag, then step
            const int t = tbase + i;
            pout[t] = (float)tag;
            tag = bp[t * NK + tag];
        }
    }
}

extern "C" void kernel_launch(void* const* d_in, const int* in_sizes, int n_in,
                              void* d_out, int out_size, void* d_ws, size_t ws_size,
                              hipStream_t stream) {
    (void)in_sizes; (void)n_in; (void)d_ws; (void)ws_size; (void)out_size;
    const float* feats = (const float*)d_in[0];
    const float* trans = (const float*)d_in[1];
    float* out = (float*)d_out;
    crf_fused<<<dim3(NB), dim3(128), 0, stream>>>(feats, trans, out);
}